// Round 13
// baseline (451.597 us; speedup 1.0000x reference)
//
#include <hip/hip_runtime.h>
#include <hip/hip_bf16.h>
#include <stdint.h>

#define D 512
#define BATCH 256
#define SEQ 512
// M = BATCH*SEQ = 131072

typedef __attribute__((ext_vector_type(8))) short short8;
typedef __attribute__((ext_vector_type(4))) float floatx4;

__device__ __forceinline__ float bf2f(unsigned short u) {
    union { unsigned int i; float f; } x; x.i = ((unsigned int)u) << 16; return x.f;
}
__device__ __forceinline__ unsigned short f2bf(float f) {
    union { float f; unsigned int i; } x; x.f = f;
    unsigned int i = x.i;
    unsigned int lsb = (i >> 16) & 1u;
    i += 0x7fffu + lsb;
    return (unsigned short)(i >> 16);
}

__device__ __forceinline__ float wred_sum(float v) {
    #pragma unroll
    for (int o = 32; o; o >>= 1) v += __shfl_xor(v, o, 64);
    return v;
}
__device__ __forceinline__ float gred_sum16(float v) {   // reduce within 16-lane group
    #pragma unroll
    for (int o = 8; o; o >>= 1) v += __shfl_xor(v, o, 64);
    return v;
}

__device__ __forceinline__ void llds16(const void* g, void* l) {
    auto gp = (const __attribute__((address_space(1))) void*)(g);
    auto lp = (__attribute__((address_space(3))) void*)(uintptr_t)(l);
    __builtin_amdgcn_global_load_lds(gp, lp, 16, 0, 0);
}

#define FENCE() asm volatile("" ::: "memory")
#define BARRIER() do { FENCE(); __builtin_amdgcn_s_barrier(); FENCE(); } while (0)

template<int WN>
__device__ __forceinline__ void waitvm() {
    if constexpr (WN == 10)     asm volatile("s_waitcnt vmcnt(10)" ::: "memory");
    else if constexpr (WN == 8) asm volatile("s_waitcnt vmcnt(8)" ::: "memory");
    else if constexpr (WN == 4) asm volatile("s_waitcnt vmcnt(4)" ::: "memory");
    else if constexpr (WN == 0) asm volatile("s_waitcnt vmcnt(0)" ::: "memory");
}

// ---------------- hop-0 scores: f32 state, q from global; writes bf16 copy ----------------
// Also converts W (f32 -> bf16) spread across the grid: 1 float4 per thread.
__global__ __launch_bounds__(1024)
void scores0_kernel(const float* __restrict__ state, const float* __restrict__ query,
                    float* __restrict__ dist_out, unsigned short* __restrict__ s_bf_out,
                    const float* __restrict__ W, unsigned short* __restrict__ Wb) {
    const int b = blockIdx.x, t = threadIdx.x, lane = t & 63, w = t >> 6;
    const int g = lane >> 4, ll = lane & 15;
    __shared__ float sc[SEQ];
    __shared__ float red[8];
    __shared__ float m_s, sum_s;

    {
        const int wi = b * 1024 + t;
        if (wi < 3 * D * D / 4) {
            float4 v = *(const float4*)(W + (size_t)wi * 4);
            ushort4 o;
            o.x = f2bf(v.x); o.y = f2bf(v.y); o.z = f2bf(v.z); o.w = f2bf(v.w);
            *(ushort4*)(Wb + (size_t)wi * 4) = o;
        }
    }

    float qv[4][8];
    {
        const float* qp = query + (size_t)b * D + ll * 8;
        #pragma unroll
        for (int j = 0; j < 4; ++j) {
            float4 a = *(const float4*)(qp + j * 128);
            float4 c = *(const float4*)(qp + j * 128 + 4);
            qv[j][0]=a.x; qv[j][1]=a.y; qv[j][2]=a.z; qv[j][3]=a.w;
            qv[j][4]=c.x; qv[j][5]=c.y; qv[j][6]=c.z; qv[j][7]=c.w;
        }
    }
    float qn2 = 0.f;
    #pragma unroll
    for (int j = 0; j < 4; ++j)
        #pragma unroll
        for (int e = 0; e < 8; ++e) qn2 += qv[j][e] * qv[j][e];
    const float qn = sqrtf(gred_sum16(qn2));

    const size_t bbase = (size_t)b * (SEQ * D);
    #pragma unroll 2
    for (int i = 0; i < 8; ++i) {
        const int row = w * 32 + i * 4 + g;
        const float* rp = state + bbase + (size_t)row * D + ll * 8;
        unsigned short* op = s_bf_out + bbase + (size_t)row * D + ll * 8;
        float dot = 0.f, nr = 0.f;
        #pragma unroll
        for (int j = 0; j < 4; ++j) {
            float4 a = *(const float4*)(rp + j * 128);
            float4 c = *(const float4*)(rp + j * 128 + 4);
            float v[8] = {a.x, a.y, a.z, a.w, c.x, c.y, c.z, c.w};
            short8 wv;
            #pragma unroll
            for (int e = 0; e < 8; ++e) wv[e] = (short)f2bf(v[e]);
            *(short8*)(op + j * 128) = wv;
            #pragma unroll
            for (int e = 0; e < 8; ++e) { dot += v[e] * qv[j][e]; nr += v[e] * v[e]; }
        }
        dot = gred_sum16(dot);
        nr  = gred_sum16(nr);
        if (ll == 0) sc[row] = 10.f * dot / fmaxf(qn * sqrtf(nr), 1e-8f);
    }
    __syncthreads();

    float sv = 0.f, ev = 0.f;
    if (t < 512) {
        sv = sc[t];
        float m = sv;
        #pragma unroll
        for (int o = 32; o; o >>= 1) m = fmaxf(m, __shfl_xor(m, o, 64));
        if (lane == 0) red[w] = m;
    }
    __syncthreads();
    if (t == 0) {
        float mm = red[0];
        #pragma unroll
        for (int k = 1; k < 8; ++k) mm = fmaxf(mm, red[k]);
        m_s = mm;
    }
    __syncthreads();
    if (t < 512) {
        ev = __expf(sv - m_s);
        float es = wred_sum(ev);
        if (lane == 0) red[w] = es;
    }
    __syncthreads();
    if (t == 0) {
        float s = 0.f;
        #pragma unroll
        for (int k = 0; k < 8; ++k) s += red[k];
        sum_s = s;
    }
    __syncthreads();
    if (t < 512) dist_out[b * SEQ + t] = ev / sum_s;
}

// ---------------- fused: agg-reduce + residual + LayerNorm + scores + softmax ----------------
__global__ __launch_bounds__(1024)
void fused_kernel(const unsigned short* __restrict__ S, const float* __restrict__ part,
                  const float* __restrict__ q_in, const float* __restrict__ gamma,
                  const float* __restrict__ beta, float* __restrict__ q_out,
                  float* __restrict__ dist_out) {
    const int b = blockIdx.x, t = threadIdx.x, lane = t & 63, w = t >> 6;
    const int g = lane >> 4, ll = lane & 15;
    __shared__ float qs[D];
    __shared__ float sc[SEQ];
    __shared__ float red[8];
    __shared__ float mu_s, rstd_s, qn_s, m_s, sum_s;

    float x = 0.f;
    if (t < 512) {
        const float a = part[(size_t)b * D + t] + part[(size_t)(BATCH * D) + (size_t)b * D + t];
        x = q_in[(size_t)b * D + t] + a;
        float sm = wred_sum(x);
        if (lane == 0) red[w] = sm;
    }
    __syncthreads();
    if (t == 0) mu_s = (red[0]+red[1]+red[2]+red[3]+red[4]+red[5]+red[6]+red[7]) * (1.f / 512.f);
    __syncthreads();
    if (t < 512) {
        const float d = x - mu_s;
        float vv = wred_sum(d * d);
        if (lane == 0) red[w] = vv;
    }
    __syncthreads();
    if (t == 0) rstd_s = rsqrtf((red[0]+red[1]+red[2]+red[3]+red[4]+red[5]+red[6]+red[7]) * (1.f / 512.f) + 1e-5f);
    __syncthreads();
    if (t < 512) {
        const float y = (x - mu_s) * rstd_s * gamma[t] + beta[t];
        q_out[(size_t)b * D + t] = y;
        qs[t] = y;
        float s2 = wred_sum(y * y);
        if (lane == 0) red[w] = s2;
    }
    __syncthreads();
    if (t == 0) qn_s = sqrtf(red[0]+red[1]+red[2]+red[3]+red[4]+red[5]+red[6]+red[7]);
    __syncthreads();

    float qv[4][8];
    #pragma unroll
    for (int j = 0; j < 4; ++j) {
        float4 a = *(const float4*)&qs[j * 128 + ll * 8];
        float4 c = *(const float4*)&qs[j * 128 + ll * 8 + 4];
        qv[j][0]=a.x; qv[j][1]=a.y; qv[j][2]=a.z; qv[j][3]=a.w;
        qv[j][4]=c.x; qv[j][5]=c.y; qv[j][6]=c.z; qv[j][7]=c.w;
    }
    const float qn = qn_s;
    const size_t bbase = (size_t)b * (SEQ * D);
    #pragma unroll 2
    for (int i = 0; i < 8; ++i) {
        const int row = w * 32 + i * 4 + g;
        const unsigned short* rp = S + bbase + (size_t)row * D + ll * 8;
        float dot = 0.f, nr = 0.f;
        #pragma unroll
        for (int j = 0; j < 4; ++j) {
            short8 wv = *(const short8*)(rp + j * 128);
            #pragma unroll
            for (int e = 0; e < 8; ++e) {
                const float v = bf2f((unsigned short)wv[e]);
                dot += v * qv[j][e];
                nr += v * v;
            }
        }
        dot = gred_sum16(dot);
        nr  = gred_sum16(nr);
        if (ll == 0) sc[row] = 10.f * dot / fmaxf(qn * sqrtf(nr), 1e-8f);
    }
    __syncthreads();

    float sv = 0.f, ev = 0.f;
    if (t < 512) {
        sv = sc[t];
        float m = sv;
        #pragma unroll
        for (int o = 32; o; o >>= 1) m = fmaxf(m, __shfl_xor(m, o, 64));
        if (lane == 0) red[w] = m;
    }
    __syncthreads();
    if (t == 0) {
        float mm = red[0];
        #pragma unroll
        for (int k = 1; k < 8; ++k) mm = fmaxf(mm, red[k]);
        m_s = mm;
    }
    __syncthreads();
    if (t < 512) {
        ev = __expf(sv - m_s);
        float es = wred_sum(ev);
        if (lane == 0) red[w] = es;
    }
    __syncthreads();
    if (t == 0) {
        float s = 0.f;
        #pragma unroll
        for (int k = 0; k < 8; ++k) s += red[k];
        sum_s = s;
    }
    __syncthreads();
    if (t < 512) dist_out[b * SEQ + t] = ev / sum_s;
}

// ---------------- GEMM: 256x256 tile, 8 waves, BK=32, depth-3 counted-vmcnt ----------------
// 16 K-tiles of 32; 4 LDS buffers (128 KB); tile kt stages tile kt+3 (A @ p0,
// B @ p1) -> prefetch lead ~6 phases (~700 ns) covers HBM latency.  One counted
// wait per K-tile: steady queue after stage = 14 -> vmcnt(10); tail 8/4/0.
// Swizzle: LDS chunk (r,c) holds global chunk c ^ ((r>>1)&3); read chunk
// lg ^ ((rr>>1)&3): lanes rr/rr+8 alias (2-way = free), all else distinct.
#define NKT32 16

#define STA32(BUF, KT) { \
    llds16(pA0 + (KT) * 32,                   &AsL[BUF][t * 8]); \
    llds16(pA0 + (size_t)128 * D + (KT) * 32, &AsL[BUF][4096 + t * 8]); }
#define STB32(BUF, KT) { \
    llds16(pB0 + (KT) * 32,                   &BsL[BUF][t * 8]); \
    llds16(pB0 + (size_t)128 * D + (KT) * 32, &BsL[BUF][4096 + t * 8]); }

#define LDAF32(BUF, MH) { _Pragma("unroll") for (int j = 0; j < 4; ++j) \
    af[j] = *(const short8*)&AsL[BUF][(MH) * 4096 + aoff[j]]; }
#define LDBF32(BUF) { _Pragma("unroll") for (int ni = 0; ni < 4; ++ni) \
    bfr[ni] = *(const short8*)&BsL[BUF][boff[ni]]; }

#define MMQ32(MH) { __builtin_amdgcn_s_setprio(1); \
    _Pragma("unroll") for (int j = 0; j < 4; ++j) \
    _Pragma("unroll") for (int ni = 0; ni < 4; ++ni) \
        acc[(MH) * 4 + j][ni] = __builtin_amdgcn_mfma_f32_16x16x32_bf16( \
            af[j], bfr[ni], acc[(MH) * 4 + j][ni], 0, 0, 0); \
    __builtin_amdgcn_s_setprio(0); }

__global__ __launch_bounds__(512, 2)
void gemm_kernel(const unsigned short* __restrict__ A, const unsigned short* __restrict__ Bt,
                 const float* __restrict__ bias, const float* __restrict__ dist,
                 unsigned short* __restrict__ C, float* __restrict__ part) {
    __shared__ __align__(16) unsigned short AsL[4][256 * 32];   // 64 KB
    __shared__ __align__(16) unsigned short BsL[4][256 * 32];   // 64 KB
    __shared__ float dls[256];
    __shared__ float agg_lds[2][256];

    const int t = threadIdx.x, lane = t & 63, wid = t >> 6;
    const int wr = wid >> 2, wc = wid & 3;
    const int rr = lane & 15, lg = lane >> 4;
    // XCD-pairing swizzle: blocks sharing an A-panel are 8 dispatch-slots apart.
    const int bid = blockIdx.x;
    const int xcd = bid & 7, j8 = bid >> 3;
    const int nB = j8 & 1;
    const int mB = xcd * 64 + (j8 >> 1);
    const size_t tileM = (size_t)mB * 256;
    const int tileN = nB * 256;

    float b_r[4];
    #pragma unroll
    for (int ni = 0; ni < 4; ++ni) b_r[ni] = bias[tileN + (ni * 4 + wc) * 16 + rr];

    if (t < 128) {
        float2 v = *(const float2*)&dist[tileM + 2 * t];
        dls[2 * t] = v.x; dls[2 * t + 1] = v.y;
    }
    asm volatile("s_waitcnt lgkmcnt(0)" ::: "memory");

    // staging source (inverse-swizzled global source, rule #21)
    const int srow = t >> 2, sc4 = t & 3;
    const int gc = sc4 ^ ((srow >> 1) & 3);
    const unsigned short* pA0 = A + (tileM + srow) * D + gc * 8;
    const unsigned short* pB0 = Bt + (size_t)(tileN + srow) * D + gc * 8;

    // fragment read offsets (shorts), swizzled k-chunk
    const int kx = (lg ^ ((rr >> 1) & 3)) * 8;
    int aoff[4], boff[4];
    #pragma unroll
    for (int j = 0; j < 4; ++j) aoff[j] = ((j * 2 + wr) * 16 + rr) * 32 + kx;
    #pragma unroll
    for (int ni = 0; ni < 4; ++ni) boff[ni] = (((ni * 4 + wc) * 16 + rr) & 255) * 32 + kx
                                              + ((((ni * 4 + wc) * 16 + rr) >> 8) * 0);
    // (col = (ni*4+wc)*16 + rr is always < 256; expression kept simple)

    floatx4 acc[8][4];
    #pragma unroll
    for (int i = 0; i < 8; ++i)
        #pragma unroll
        for (int j = 0; j < 4; ++j) acc[i][j] = {0.f, 0.f, 0.f, 0.f};

    short8 af[4], bfr[4];

    // prologue: stage tiles 0,1,2 fully (12 loads)
    STA32(0, 0); STB32(0, 0);
    STA32(1, 1); STB32(1, 1);
    STA32(2, 2); STB32(2, 2);

    for (int kt = 0; kt < NKT32; ++kt) {
        const int rb = kt & 3;
        // p0: stage A of kt+3; counted wait lands tile kt; compute M-half 0
        if (kt < NKT32 - 3) { STA32((kt + 3) & 3, kt + 3); }
        if (kt < NKT32 - 3)      waitvm<10>();
        else if (kt == NKT32 - 3) waitvm<8>();
        else if (kt == NKT32 - 2) waitvm<4>();
        else                      waitvm<0>();
        BARRIER();
        LDAF32(rb, 0); LDBF32(rb);
        MMQ32(0);
        BARRIER();
        // p1: stage B of kt+3; compute M-half 1 (B frags held)
        if (kt < NKT32 - 3) { STB32((kt + 3) & 3, kt + 3); }
        LDAF32(rb, 1);
        MMQ32(1);
        BARRIER();
    }
    __syncthreads();

    // epilogue: bias + lrelu + C store + fused agg partials
    float pacc[4] = {0.f, 0.f, 0.f, 0.f};
    #pragma unroll
    for (int mi = 0; mi < 8; ++mi) {
        const int rowb = (mi * 2 + wr) * 16 + lg * 4;
        const float4 dv = *(const float4*)&dls[rowb];
        #pragma unroll
        for (int ni = 0; ni < 4; ++ni) {
            const int col = tileN + (ni * 4 + wc) * 16 + rr;
            #pragma unroll
            for (int r2 = 0; r2 < 4; ++r2) {
                float v = acc[mi][ni][r2] + b_r[ni];
                v = v >= 0.f ? v : 0.01f * v;
                C[(tileM + rowb + r2) * D + col] = f2bf(v);
                pacc[ni] += (&dv.x)[r2] * v;
            }
        }
    }
    #pragma unroll
    for (int ni = 0; ni < 4; ++ni) {
        float p = pacc[ni];
        p += __shfl_xor(p, 16, 64);
        p += __shfl_xor(p, 32, 64);
        if (lg == 0) agg_lds[wr][(ni * 4 + wc) * 16 + rr] = p;
    }
    __syncthreads();
    if (t < 256) {
        const int b = mB >> 1;
        const float s = agg_lds[0][t] + agg_lds[1][t];
        part[(size_t)(mB & 1) * (BATCH * D) + (size_t)b * D + tileN + t] = s;
    }
}

extern "C" void kernel_launch(void* const* d_in, const int* in_sizes, int n_in,
                              void* d_out, int out_size, void* d_ws, size_t ws_size,
                              hipStream_t stream) {
    const float* query = (const float*)d_in[0];
    const float* state = (const float*)d_in[1];
    const float* W     = (const float*)d_in[2];
    const float* bias  = (const float*)d_in[3];
    const float* gamma = (const float*)d_in[4];
    const float* beta  = (const float*)d_in[5];

    float* out_q    = (float*)d_out;
    float* out_dist = (float*)d_out + BATCH * SEQ;

    char* ws = (char*)d_ws;
    const size_t SBYTES = (size_t)BATCH * SEQ * D * 2;   // 134,217,728
    unsigned short* sA = (unsigned short*)ws;
    unsigned short* sB = (unsigned short*)(ws + SBYTES);
    char* ext = ws + 2 * SBYTES;
    float* dist = (float*)ext;                           // 512 KB
    float* qbuf = (float*)(ext + 524288);                // 512 KB
    float* part = (float*)(ext + 2 * 524288);            // 2 slots * 512 KB = 1 MB
    unsigned short* Wb = (unsigned short*)(ext + 4 * 524288);  // 1.5 MB

    dim3 ggrid(BATCH * SEQ / 256 * 2);   // 1024 blocks

    // hop 0 (scores0 also converts W -> bf16)
    scores0_kernel<<<BATCH, 1024, 0, stream>>>(state, query, dist, sA, W, Wb);
    gemm_kernel<<<ggrid, 512, 0, stream>>>(sA, Wb, bias, dist, sB, part);
    // hop 1
    fused_kernel<<<BATCH, 1024, 0, stream>>>(sB, part, query, gamma, beta, qbuf, dist);
    gemm_kernel<<<ggrid, 512, 0, stream>>>(sB, Wb + D * D, bias + D, dist, sA, part);
    // hop 2
    fused_kernel<<<BATCH, 1024, 0, stream>>>(sA, part, qbuf, gamma, beta, qbuf, dist);
    gemm_kernel<<<ggrid, 512, 0, stream>>>(sA, Wb + 2 * D * D, bias + 2 * D, dist, sB, part);
    // hop 3 epilogue: final LN -> out_q, final dist -> out_dist
    fused_kernel<<<BATCH, 1024, 0, stream>>>(sB, part, qbuf, gamma, beta, out_q, out_dist);
}

// Round 14
// 417.928 us; speedup vs baseline: 1.0806x; 1.0806x over previous
//
#include <hip/hip_runtime.h>
#include <hip/hip_bf16.h>
#include <stdint.h>

#define D 512
#define BATCH 256
#define SEQ 512
// M = BATCH*SEQ = 131072

typedef __attribute__((ext_vector_type(8))) short short8;
typedef __attribute__((ext_vector_type(4))) float floatx4;

__device__ __forceinline__ float bf2f(unsigned short u) {
    union { unsigned int i; float f; } x; x.i = ((unsigned int)u) << 16; return x.f;
}
__device__ __forceinline__ unsigned short f2bf(float f) {
    union { float f; unsigned int i; } x; x.f = f;
    unsigned int i = x.i;
    unsigned int lsb = (i >> 16) & 1u;
    i += 0x7fffu + lsb;
    return (unsigned short)(i >> 16);
}

__device__ __forceinline__ float wred_sum(float v) {
    #pragma unroll
    for (int o = 32; o; o >>= 1) v += __shfl_xor(v, o, 64);
    return v;
}
__device__ __forceinline__ float gred_sum16(float v) {   // reduce within 16-lane group
    #pragma unroll
    for (int o = 8; o; o >>= 1) v += __shfl_xor(v, o, 64);
    return v;
}

__device__ __forceinline__ void llds16(const void* g, void* l) {
    auto gp = (const __attribute__((address_space(1))) void*)(g);
    auto lp = (__attribute__((address_space(3))) void*)(uintptr_t)(l);
    __builtin_amdgcn_global_load_lds(gp, lp, 16, 0, 0);
}

#define FENCE() asm volatile("" ::: "memory")
#define BARRIER() do { FENCE(); __builtin_amdgcn_s_barrier(); FENCE(); } while (0)

template<int WN>
__device__ __forceinline__ void waitvm() {
    if constexpr (WN == 6)      asm volatile("s_waitcnt vmcnt(6)" ::: "memory");
    else if constexpr (WN == 4) asm volatile("s_waitcnt vmcnt(4)" ::: "memory");
    else if constexpr (WN == 2) asm volatile("s_waitcnt vmcnt(2)" ::: "memory");
    else if constexpr (WN == 0) asm volatile("s_waitcnt vmcnt(0)" ::: "memory");
}

// ---------------- hop-0 scores: f32 state, q from global; writes bf16 copy ----------------
// Also converts W (f32 -> bf16) spread across the grid: 1 float4 per thread.
__global__ __launch_bounds__(1024)
void scores0_kernel(const float* __restrict__ state, const float* __restrict__ query,
                    float* __restrict__ dist_out, unsigned short* __restrict__ s_bf_out,
                    const float* __restrict__ W, unsigned short* __restrict__ Wb) {
    const int b = blockIdx.x, t = threadIdx.x, lane = t & 63, w = t >> 6;
    const int g = lane >> 4, ll = lane & 15;
    __shared__ float sc[SEQ];
    __shared__ float red[8];
    __shared__ float m_s, sum_s;

    {
        const int wi = b * 1024 + t;
        if (wi < 3 * D * D / 4) {
            float4 v = *(const float4*)(W + (size_t)wi * 4);
            ushort4 o;
            o.x = f2bf(v.x); o.y = f2bf(v.y); o.z = f2bf(v.z); o.w = f2bf(v.w);
            *(ushort4*)(Wb + (size_t)wi * 4) = o;
        }
    }

    float qv[4][8];
    {
        const float* qp = query + (size_t)b * D + ll * 8;
        #pragma unroll
        for (int j = 0; j < 4; ++j) {
            float4 a = *(const float4*)(qp + j * 128);
            float4 c = *(const float4*)(qp + j * 128 + 4);
            qv[j][0]=a.x; qv[j][1]=a.y; qv[j][2]=a.z; qv[j][3]=a.w;
            qv[j][4]=c.x; qv[j][5]=c.y; qv[j][6]=c.z; qv[j][7]=c.w;
        }
    }
    float qn2 = 0.f;
    #pragma unroll
    for (int j = 0; j < 4; ++j)
        #pragma unroll
        for (int e = 0; e < 8; ++e) qn2 += qv[j][e] * qv[j][e];
    const float qn = sqrtf(gred_sum16(qn2));

    const size_t bbase = (size_t)b * (SEQ * D);
    #pragma unroll 2
    for (int i = 0; i < 8; ++i) {
        const int row = w * 32 + i * 4 + g;
        const float* rp = state + bbase + (size_t)row * D + ll * 8;
        unsigned short* op = s_bf_out + bbase + (size_t)row * D + ll * 8;
        float dot = 0.f, nr = 0.f;
        #pragma unroll
        for (int j = 0; j < 4; ++j) {
            float4 a = *(const float4*)(rp + j * 128);
            float4 c = *(const float4*)(rp + j * 128 + 4);
            float v[8] = {a.x, a.y, a.z, a.w, c.x, c.y, c.z, c.w};
            short8 wv;
            #pragma unroll
            for (int e = 0; e < 8; ++e) wv[e] = (short)f2bf(v[e]);
            *(short8*)(op + j * 128) = wv;
            #pragma unroll
            for (int e = 0; e < 8; ++e) { dot += v[e] * qv[j][e]; nr += v[e] * v[e]; }
        }
        dot = gred_sum16(dot);
        nr  = gred_sum16(nr);
        if (ll == 0) sc[row] = 10.f * dot / fmaxf(qn * sqrtf(nr), 1e-8f);
    }
    __syncthreads();

    float sv = 0.f, ev = 0.f;
    if (t < 512) {
        sv = sc[t];
        float m = sv;
        #pragma unroll
        for (int o = 32; o; o >>= 1) m = fmaxf(m, __shfl_xor(m, o, 64));
        if (lane == 0) red[w] = m;
    }
    __syncthreads();
    if (t == 0) {
        float mm = red[0];
        #pragma unroll
        for (int k = 1; k < 8; ++k) mm = fmaxf(mm, red[k]);
        m_s = mm;
    }
    __syncthreads();
    if (t < 512) {
        ev = __expf(sv - m_s);
        float es = wred_sum(ev);
        if (lane == 0) red[w] = es;
    }
    __syncthreads();
    if (t == 0) {
        float s = 0.f;
        #pragma unroll
        for (int k = 0; k < 8; ++k) s += red[k];
        sum_s = s;
    }
    __syncthreads();
    if (t < 512) dist_out[b * SEQ + t] = ev / sum_s;
}

// ---------------- fused: agg-reduce + residual + LayerNorm + scores + softmax ----------------
__global__ __launch_bounds__(1024)
void fused_kernel(const unsigned short* __restrict__ S, const float* __restrict__ part,
                  const float* __restrict__ q_in, const float* __restrict__ gamma,
                  const float* __restrict__ beta, float* __restrict__ q_out,
                  float* __restrict__ dist_out) {
    const int b = blockIdx.x, t = threadIdx.x, lane = t & 63, w = t >> 6;
    const int g = lane >> 4, ll = lane & 15;
    __shared__ float qs[D];
    __shared__ float sc[SEQ];
    __shared__ float red[8];
    __shared__ float mu_s, rstd_s, qn_s, m_s, sum_s;

    float x = 0.f;
    if (t < 512) {
        const float a = part[(size_t)b * D + t] + part[(size_t)(BATCH * D) + (size_t)b * D + t];
        x = q_in[(size_t)b * D + t] + a;
        float sm = wred_sum(x);
        if (lane == 0) red[w] = sm;
    }
    __syncthreads();
    if (t == 0) mu_s = (red[0]+red[1]+red[2]+red[3]+red[4]+red[5]+red[6]+red[7]) * (1.f / 512.f);
    __syncthreads();
    if (t < 512) {
        const float d = x - mu_s;
        float vv = wred_sum(d * d);
        if (lane == 0) red[w] = vv;
    }
    __syncthreads();
    if (t == 0) rstd_s = rsqrtf((red[0]+red[1]+red[2]+red[3]+red[4]+red[5]+red[6]+red[7]) * (1.f / 512.f) + 1e-5f);
    __syncthreads();
    if (t < 512) {
        const float y = (x - mu_s) * rstd_s * gamma[t] + beta[t];
        q_out[(size_t)b * D + t] = y;
        qs[t] = y;
        float s2 = wred_sum(y * y);
        if (lane == 0) red[w] = s2;
    }
    __syncthreads();
    if (t == 0) qn_s = sqrtf(red[0]+red[1]+red[2]+red[3]+red[4]+red[5]+red[6]+red[7]);
    __syncthreads();

    float qv[4][8];
    #pragma unroll
    for (int j = 0; j < 4; ++j) {
        float4 a = *(const float4*)&qs[j * 128 + ll * 8];
        float4 c = *(const float4*)&qs[j * 128 + ll * 8 + 4];
        qv[j][0]=a.x; qv[j][1]=a.y; qv[j][2]=a.z; qv[j][3]=a.w;
        qv[j][4]=c.x; qv[j][5]=c.y; qv[j][6]=c.z; qv[j][7]=c.w;
    }
    const float qn = qn_s;
    const size_t bbase = (size_t)b * (SEQ * D);
    #pragma unroll 2
    for (int i = 0; i < 8; ++i) {
        const int row = w * 32 + i * 4 + g;
        const unsigned short* rp = S + bbase + (size_t)row * D + ll * 8;
        float dot = 0.f, nr = 0.f;
        #pragma unroll
        for (int j = 0; j < 4; ++j) {
            short8 wv = *(const short8*)(rp + j * 128);
            #pragma unroll
            for (int e = 0; e < 8; ++e) {
                const float v = bf2f((unsigned short)wv[e]);
                dot += v * qv[j][e];
                nr += v * v;
            }
        }
        dot = gred_sum16(dot);
        nr  = gred_sum16(nr);
        if (ll == 0) sc[row] = 10.f * dot / fmaxf(qn * sqrtf(nr), 1e-8f);
    }
    __syncthreads();

    float sv = 0.f, ev = 0.f;
    if (t < 512) {
        sv = sc[t];
        float m = sv;
        #pragma unroll
        for (int o = 32; o; o >>= 1) m = fmaxf(m, __shfl_xor(m, o, 64));
        if (lane == 0) red[w] = m;
    }
    __syncthreads();
    if (t == 0) {
        float mm = red[0];
        #pragma unroll
        for (int k = 1; k < 8; ++k) mm = fmaxf(mm, red[k]);
        m_s = mm;
    }
    __syncthreads();
    if (t < 512) {
        ev = __expf(sv - m_s);
        float es = wred_sum(ev);
        if (lane == 0) red[w] = es;
    }
    __syncthreads();
    if (t == 0) {
        float s = 0.f;
        #pragma unroll
        for (int k = 0; k < 8; ++k) s += red[k];
        sum_s = s;
    }
    __syncthreads();
    if (t < 512) dist_out[b * SEQ + t] = ev / sum_s;
}

// ---------------- GEMM: 256x256 tile, 8 waves, 4-phase/K-tile counted-vmcnt ----------------
// Proven best (r12, 418.5 µs): 4-phase stagger + B-fragment holding (bfr0/bfr1),
// ds_read_b128 24/wave/K-tile, stage order A0,B0,B1,A1, vmcnt(6) waits, XCD pairing.
#define NKT 8   // K-tiles of 64

#define STA(BUF, H, KT) { const unsigned short* s_ = pA + (H) * 128 * D + (KT) * 64; \
    llds16(s_, &AsL[BUF][H][t * 8]); llds16(s_ + 64 * D, &AsL[BUF][H][t * 8 + 4096]); }
#define STB(BUF, H, KT) { const unsigned short* s_ = pB + (H) * 128 * D + (KT) * 64; \
    llds16(s_, &BsL[BUF][H][t * 8]); llds16(s_ + 64 * D, &BsL[BUF][H][t * 8 + 4096]); }

#define LDAF(BUF, MH) { _Pragma("unroll") for (int j = 0; j < 4; ++j) { \
    af[j][0] = *(const short8*)&AsL[BUF][MH][aoff[j] + xk0]; \
    af[j][1] = *(const short8*)&AsL[BUF][MH][aoff[j] + xk1]; } }
#define LDBF0(BUF) { _Pragma("unroll") for (int i = 0; i < 2; ++i) { \
    bfr0[i][0] = *(const short8*)&BsL[BUF][0][boff[i] + xk0]; \
    bfr0[i][1] = *(const short8*)&BsL[BUF][0][boff[i] + xk1]; } }
#define LDBF1(BUF) { _Pragma("unroll") for (int i = 0; i < 2; ++i) { \
    bfr1[i][0] = *(const short8*)&BsL[BUF][1][boff[i] + xk0]; \
    bfr1[i][1] = *(const short8*)&BsL[BUF][1][boff[i] + xk1]; } }

#define MMQ(MH, NH, BFR) { __builtin_amdgcn_s_setprio(1); \
    _Pragma("unroll") for (int kh = 0; kh < 2; ++kh) \
    _Pragma("unroll") for (int j = 0; j < 4; ++j) \
    _Pragma("unroll") for (int i = 0; i < 2; ++i) \
        acc[(MH) * 4 + j][(NH) * 2 + i] = __builtin_amdgcn_mfma_f32_16x16x32_bf16( \
            af[j][kh], BFR[i][kh], acc[(MH) * 4 + j][(NH) * 2 + i], 0, 0, 0); \
    __builtin_amdgcn_s_setprio(0); }

__global__ __launch_bounds__(512, 2)
void gemm_kernel(const unsigned short* __restrict__ A, const unsigned short* __restrict__ Bt,
                 const float* __restrict__ bias, const float* __restrict__ dist,
                 unsigned short* __restrict__ C, float* __restrict__ part) {
    __shared__ __align__(16) unsigned short AsL[2][2][128 * 64];   // 64 KB
    __shared__ __align__(16) unsigned short BsL[2][2][128 * 64];   // 64 KB
    __shared__ float dls[256];
    __shared__ float agg_lds[2][256];

    const int t = threadIdx.x, lane = t & 63, wid = t >> 6;
    const int wr = wid >> 2, wc = wid & 3;
    const int rr = lane & 15, lg = lane >> 4;
    // XCD-pairing swizzle: blocks sharing an A-panel are 8 dispatch-slots apart.
    const int bid = blockIdx.x;
    const int xcd = bid & 7, j8 = bid >> 3;
    const int nB = j8 & 1;
    const int mB = xcd * 64 + (j8 >> 1);
    const size_t tileM = (size_t)mB * 256;
    const int tileN = nB * 256;

    float b_r[4];
    #pragma unroll
    for (int ni = 0; ni < 4; ++ni) b_r[ni] = bias[tileN + (ni * 4 + wc) * 16 + rr];

    if (t < 128) {
        float2 v = *(const float2*)&dist[tileM + 2 * t];
        dls[2 * t] = v.x; dls[2 * t + 1] = v.y;
    }
    asm volatile("s_waitcnt lgkmcnt(0)" ::: "memory");

    // staging source (inverse-swizzled global source, rule #21)
    const int srow = t >> 3, gc = (t & 7) ^ (srow & 7);
    const unsigned short* pA = A + (tileM + srow) * D + gc * 8;
    const unsigned short* pB = Bt + (size_t)(tileN + srow) * D + gc * 8;

    int aoff[4], boff[2];
    #pragma unroll
    for (int j = 0; j < 4; ++j) aoff[j] = ((j * 2 + wr) * 16 + rr) * 64;
    #pragma unroll
    for (int i = 0; i < 2; ++i) boff[i] = ((i * 4 + wc) * 16 + rr) * 64;
    const int xk0 = ((lg) ^ (rr & 7)) * 8;
    const int xk1 = ((4 + lg) ^ (rr & 7)) * 8;

    floatx4 acc[8][4];
    #pragma unroll
    for (int i = 0; i < 8; ++i)
        #pragma unroll
        for (int j = 0; j < 4; ++j) acc[i][j] = {0.f, 0.f, 0.f, 0.f};

    short8 af[4][2], bfr0[2][2], bfr1[2][2];

    // prologue: tile 0 halves, order A0,B0,B1,A1
    STA(0, 0, 0); STB(0, 0, 0); STB(0, 1, 0); STA(0, 1, 0);

    for (int kt = 0; kt < NKT - 1; ++kt) {
        const int rb = kt & 1, sb = rb ^ 1, nk = kt + 1;
        // p0: quadrant (0,0); stage A0 of kt+1
        STA(sb, 0, nk); waitvm<6>(); BARRIER();
        LDAF(rb, 0); LDBF0(rb); MMQ(0, 0, bfr0); BARRIER();
        // p1: quadrant (0,1); stage B0
        STB(sb, 0, nk); waitvm<6>(); BARRIER();
        LDBF1(rb); MMQ(0, 1, bfr1); BARRIER();
        // p2: quadrant (1,0); stage B1  (B-half 0 held in bfr0)
        STB(sb, 1, nk); waitvm<6>(); BARRIER();
        LDAF(rb, 1); MMQ(1, 0, bfr0); BARRIER();
        // p3: quadrant (1,1); stage A1  (B-half 1 held in bfr1)
        STA(sb, 1, nk); BARRIER();
        MMQ(1, 1, bfr1); BARRIER();
    }
    {   // last tile (kt = 7, rb = 1): counted drain in the tail only
        waitvm<4>(); BARRIER();
        LDAF(1, 0); LDBF0(1); MMQ(0, 0, bfr0); BARRIER();
        waitvm<2>(); BARRIER();
        LDBF1(1); MMQ(0, 1, bfr1); BARRIER();
        waitvm<0>(); BARRIER();
        LDAF(1, 1); MMQ(1, 0, bfr0); BARRIER();
        MMQ(1, 1, bfr1);
    }
    __syncthreads();

    // epilogue: bias + lrelu + C store + fused agg partials
    float pacc[4] = {0.f, 0.f, 0.f, 0.f};
    #pragma unroll
    for (int mi = 0; mi < 8; ++mi) {
        const int rowb = (mi * 2 + wr) * 16 + lg * 4;
        const float4 dv = *(const float4*)&dls[rowb];
        #pragma unroll
        for (int ni = 0; ni < 4; ++ni) {
            const int col = tileN + (ni * 4 + wc) * 16 + rr;
            #pragma unroll
            for (int r2 = 0; r2 < 4; ++r2) {
                float v = acc[mi][ni][r2] + b_r[ni];
                v = v >= 0.f ? v : 0.01f * v;
                C[(tileM + rowb + r2) * D + col] = f2bf(v);
                pacc[ni] += (&dv.x)[r2] * v;
            }
        }
    }
    #pragma unroll
    for (int ni = 0; ni < 4; ++ni) {
        float p = pacc[ni];
        p += __shfl_xor(p, 16, 64);
        p += __shfl_xor(p, 32, 64);
        if (lg == 0) agg_lds[wr][(ni * 4 + wc) * 16 + rr] = p;
    }
    __syncthreads();
    if (t < 256) {
        const int b = mB >> 1;
        const float s = agg_lds[0][t] + agg_lds[1][t];
        part[(size_t)(mB & 1) * (BATCH * D) + (size_t)b * D + tileN + t] = s;
    }
}

extern "C" void kernel_launch(void* const* d_in, const int* in_sizes, int n_in,
                              void* d_out, int out_size, void* d_ws, size_t ws_size,
                              hipStream_t stream) {
    const float* query = (const float*)d_in[0];
    const float* state = (const float*)d_in[1];
    const float* W     = (const float*)d_in[2];
    const float* bias  = (const float*)d_in[3];
    const float* gamma = (const float*)d_in[4];
    const float* beta  = (const float*)d_in[5];

    float* out_q    = (float*)d_out;
    float* out_dist = (float*)d_out + BATCH * SEQ;

    char* ws = (char*)d_ws;
    const size_t SBYTES = (size_t)BATCH * SEQ * D * 2;   // 134,217,728
    unsigned short* sA = (unsigned short*)ws;
    unsigned short* sB = (unsigned short*)(ws + SBYTES);
    char* ext = ws + 2 * SBYTES;
    float* dist = (float*)ext;                           // 512 KB
    float* qbuf = (float*)(ext + 524288);                // 512 KB
    float* part = (float*)(ext + 2 * 524288);            // 2 slots * 512 KB = 1 MB
    unsigned short* Wb = (unsigned short*)(ext + 4 * 524288);  // 1.5 MB

    dim3 ggrid(BATCH * SEQ / 256 * 2);   // 1024 blocks

    // hop 0 (scores0 also converts W -> bf16)
    scores0_kernel<<<BATCH, 1024, 0, stream>>>(state, query, dist, sA, W, Wb);
    gemm_kernel<<<ggrid, 512, 0, stream>>>(sA, Wb, bias, dist, sB, part);
    // hop 1
    fused_kernel<<<BATCH, 1024, 0, stream>>>(sB, part, query, gamma, beta, qbuf, dist);
    gemm_kernel<<<ggrid, 512, 0, stream>>>(sB, Wb + D * D, bias + D, dist, sA, part);
    // hop 2
    fused_kernel<<<BATCH, 1024, 0, stream>>>(sA, part, qbuf, gamma, beta, qbuf, dist);
    gemm_kernel<<<ggrid, 512, 0, stream>>>(sA, Wb + 2 * D * D, bias + 2 * D, dist, sB, part);
    // hop 3 epilogue: final LN -> out_q, final dist -> out_dist
    fused_kernel<<<BATCH, 1024, 0, stream>>>(sB, part, qbuf, gamma, beta, out_q, out_dist);
}